// Round 6
// baseline (1634.950 us; speedup 1.0000x reference)
//
#include <hip/hip_runtime.h>

// Fuzzy c-means on MI355X. N=300000, D=64, c=64, m=2 (p=2), 25 updates + init.
// R6: (1) coalesced prep (was 50us @2.2TB/s, thread-per-row strided);
// (2) XTb transpose staged via in-register 2x2 bf16 transpose + p-fast b32 LDS
//     stores (2-way banks, free) -- kills the 8-way scatter conflict (5.25M cyc);
// (3) pass epilogue atomicAdds into one 4160-float acc; reduce+final collapse
//     into a 1-block finalize (divide, diff, check, zero acc).

#define DM 64
#define CL 64
#define MAX_ITER 25
#define NB 512
#define LDP 72                   // padded row (bf16): 144B, 16B-aligned rows

typedef __attribute__((ext_vector_type(8))) short bf16x8;   // MFMA A/B frag
typedef __attribute__((ext_vector_type(4))) float f32x4;    // MFMA C/D frag

__device__ __forceinline__ unsigned f2bf1(float f) {        // fp32 -> bf16 (RNE)
  unsigned u = __builtin_bit_cast(unsigned, f);
  return (u + 0x7FFFu + ((u >> 16) & 1u)) >> 16;
}
__device__ __forceinline__ unsigned pkbf(float a, float b) {
  return f2bf1(a) | (f2bf1(b) << 16);
}

// 64-lane sum, result uniform (lane 63 via readlane). Pure VALU (DPP).
__device__ __forceinline__ float wave_sum(float v) {
#define DPPADD(ctrl, rmask)                                                  \
  v += __builtin_bit_cast(float, __builtin_amdgcn_update_dpp(                \
           0, __builtin_bit_cast(int, v), ctrl, rmask, 0xf, false));
  DPPADD(0x111, 0xf)   // row_shr:1
  DPPADD(0x112, 0xf)   // row_shr:2
  DPPADD(0x114, 0xf)   // row_shr:4
  DPPADD(0x118, 0xf)   // row_shr:8
  DPPADD(0x142, 0xa)   // row_bcast:15
  DPPADD(0x143, 0xc)   // row_bcast:31
#undef DPPADD
  return __builtin_bit_cast(
      float, __builtin_amdgcn_readlane(__builtin_bit_cast(int, v), 63));
}

// all-lanes sum within each 16-lane group (DPP butterfly), result in all 16.
__device__ __forceinline__ float group16_sum(float v) {
#define DPPADD(ctrl)                                                         \
  v += __builtin_bit_cast(float, __builtin_amdgcn_update_dpp(                \
           0, __builtin_bit_cast(int, v), ctrl, 0xf, 0xf, false));
  DPPADD(0xB1)    // quad_perm [1,0,3,2]
  DPPADD(0x4E)    // quad_perm [2,3,0,1]
  DPPADD(0x141)   // row_half_mirror
  DPPADD(0x140)   // row_mirror
#undef DPPADD
  return v;
}

// Coalesced prep: 16 lanes per row. Lane reads one float4 (256B/row contiguous),
// x2 via DPP group16 sum, bf16 pack stored as uint2 (128B/row contiguous).
// Also zeroes acc[4160] + done.
__global__ void fcm_prep(const float* __restrict__ data, float* __restrict__ x2,
                         unsigned short* __restrict__ xbf, float* __restrict__ acc,
                         int* __restrict__ done, int N) {
  int g = blockIdx.x * blockDim.x + threadIdx.x;
  if (g < CL * DM + CL) acc[g] = 0.0f;
  if (g == CL * DM + CL) *done = 0;
  int row = g >> 4;
  int c = g & 15;
  if (row < N) {
    float4 v = *(const float4*)(data + (size_t)row * DM + c * 4);
    float s = fmaf(v.x, v.x, fmaf(v.y, v.y, fmaf(v.z, v.z, v.w * v.w)));
    s = group16_sum(s);
    if (c == 0) x2[row] = s;
    uint2 pk = {pkbf(v.x, v.y), pkbf(v.z, v.w)};
    *(uint2*)(void*)(xbf + (size_t)row * DM + c * 4) = pk;
  }
}

// Fused pass. INIT: W := u0 (raw memberships). else: W := 1/dist via MFMA GEMM1.
// Both: um = (W * rcp(rowsum))^2 -> bf16 umT -> MFMA GEMM2 -> atomic acc.
template <bool INIT>
__global__ __launch_bounds__(256, 3)
void fcm_pass(const unsigned short* __restrict__ xbf, const float* __restrict__ x2,
              const float* __restrict__ CU,   // INIT: u0[N][64]; else C[64][64]
              float* __restrict__ acc, const int* __restrict__ done,
              int N, int ntiles) {
  if (!INIT && *done) return;
  __shared__ __align__(16) unsigned short Xb[64 * LDP];   // X[p][d] bf16
  __shared__ __align__(16) unsigned short XTb[64 * LDP];  // X^T[d][p] bf16
  __shared__ __align__(16) unsigned short umT[64 * LDP];  // um^T[j][p] bf16
  __shared__ __align__(16) float rpart[4 * 64];
  __shared__ __align__(16) float rrs[64];
  __shared__ __align__(16) float x2s[64];

  const int tid  = threadIdx.x;
  const int w    = __builtin_amdgcn_readfirstlane(tid >> 6);
  const int col  = tid & 15;
  const int quad = (tid >> 4) & 3;

  // ---- per-kernel prep: C row j=16w+col -> c2[j] + bf16 B-frags ----
  bf16x8 cf0, cf1;
  float c2j = 0.0f;
  if (!INIT) {
    const float* crow = CU + (size_t)(16 * w + col) * DM;
    float4 ca = *(const float4*)(crow + quad * 8);
    float4 cb = *(const float4*)(crow + quad * 8 + 4);
    float4 cc = *(const float4*)(crow + 32 + quad * 8);
    float4 cd = *(const float4*)(crow + 32 + quad * 8 + 4);
    float cp = ca.x*ca.x + ca.y*ca.y + ca.z*ca.z + ca.w*ca.w
             + cb.x*cb.x + cb.y*cb.y + cb.z*cb.z + cb.w*cb.w
             + cc.x*cc.x + cc.y*cc.y + cc.z*cc.z + cc.w*cc.w
             + cd.x*cd.x + cd.y*cd.y + cd.z*cd.z + cd.w*cd.w;
    cp += __shfl_xor(cp, 16, 64);
    cp += __shfl_xor(cp, 32, 64);
    c2j = cp;
    union { bf16x8 v; unsigned u[4]; } P0, P1;
    P0.u[0] = pkbf(ca.x, ca.y); P0.u[1] = pkbf(ca.z, ca.w);
    P0.u[2] = pkbf(cb.x, cb.y); P0.u[3] = pkbf(cb.z, cb.w);
    P1.u[0] = pkbf(cc.x, cc.y); P1.u[1] = pkbf(cc.z, cc.w);
    P1.u[2] = pkbf(cd.x, cd.y); P1.u[3] = pkbf(cd.z, cd.w);
    cf0 = P0.v; cf1 = P1.v;
  }

  f32x4 D2[4];
#pragma unroll
  for (int dt = 0; dt < 4; dt++) D2[dt] = f32x4{0.f, 0.f, 0.f, 0.f};
  float den = 0.0f;

  for (int t = blockIdx.x; t < ntiles; t += gridDim.x) {
    const int base = t * 64;
    const int np = min(64, N - base);
    __syncthreads();   // previous iteration's LDS reads done

    // ---- Xb rows: b128 global -> b128 LDS (conflict-free) ----
    for (int i = tid; i < 512; i += 256) {
      int p = i >> 3;
      int d8 = (i & 7) * 8;
      bf16x8 v = bf16x8{0, 0, 0, 0, 0, 0, 0, 0};
      if (p < np) v = *(const bf16x8*)(xbf + (size_t)(base + p) * DM + d8);
      *(bf16x8*)(void*)&Xb[p * LDP + d8] = v;
    }
    // ---- XTb: in-register 2x2 bf16 transpose; p lane-fast b32 stores ->
    //      banks 0..31 exactly 2-way (free). Global reads hit L1 (tile 8KB). ----
#pragma unroll
    for (int it = 0; it < 4; it++) {
      int idx = it * 256 + tid;          // 0..1023
      int d = (idx >> 5) * 2;            // 0,2,..,62
      int p = (idx & 31) * 2;            // 0,2,..,62
      unsigned w0 = 0, w1 = 0;
      if (p < np)     w0 = *(const unsigned*)(xbf + (size_t)(base + p) * DM + d);
      if (p + 1 < np) w1 = *(const unsigned*)(xbf + (size_t)(base + p + 1) * DM + d);
      unsigned t0 = (w0 & 0xFFFFu) | (w1 << 16);         // XT[d][p], XT[d][p+1]
      unsigned t1 = (w0 >> 16) | (w1 & 0xFFFF0000u);     // XT[d+1][p], XT[d+1][p+1]
      *(unsigned*)(void*)&XTb[d * LDP + p] = t0;
      *(unsigned*)(void*)&XTb[(d + 1) * LDP + p] = t1;
    }
    if (tid < 64) x2s[tid] = (base + tid < N) ? x2[base + tid] : 0.0f;
    __syncthreads();

    // ---- W (MFMA C/D layout: p=pt*16+quad*4+r, j=16w+col) ----
    float W[4][4];
    if (INIT) {
#pragma unroll
      for (int pt = 0; pt < 4; pt++)
#pragma unroll
        for (int r = 0; r < 4; r++) {
          int pl = pt * 16 + quad * 4 + r;
          W[pt][r] = (pl < np)
              ? CU[(size_t)(base + pl) * CL + 16 * w + col] : 0.0f;
        }
    } else {
#pragma unroll
      for (int pt = 0; pt < 4; pt++) {
        bf16x8 a0 = *(const bf16x8*)(const void*)&Xb[(pt * 16 + col) * LDP + quad * 8];
        bf16x8 a1 = *(const bf16x8*)(const void*)&Xb[(pt * 16 + col) * LDP + 32 + quad * 8];
        f32x4 s = f32x4{0.f, 0.f, 0.f, 0.f};
        s = __builtin_amdgcn_mfma_f32_16x16x32_bf16(a0, cf0, s, 0, 0, 0);
        s = __builtin_amdgcn_mfma_f32_16x16x32_bf16(a1, cf1, s, 0, 0, 0);
        f32x4 x2v = *(const f32x4*)(const void*)&x2s[pt * 16 + quad * 4];
#pragma unroll
        for (int r = 0; r < 4; r++) {
          float dist = fmaxf(fmaf(-2.0f, s[r], x2v[r] + c2j), 0.0f);
          W[pt][r] = __builtin_amdgcn_rcpf(dist);   // d^(-p/2), p=2
        }
      }
    }

    // ---- rowsum over this wave's 16 clusters (DPP), cross-wave via LDS ----
    float rs[4][4];
#pragma unroll
    for (int pt = 0; pt < 4; pt++)
#pragma unroll
      for (int r = 0; r < 4; r++) rs[pt][r] = group16_sum(W[pt][r]);
    if (col == 0) {
#pragma unroll
      for (int pt = 0; pt < 4; pt++) {
        float4 v4 = {rs[pt][0], rs[pt][1], rs[pt][2], rs[pt][3]};
        *(float4*)(void*)&rpart[w * 64 + pt * 16 + quad * 4] = v4;
      }
    }
    __syncthreads();
    if (tid < 64) {
      float rt = rpart[tid] + rpart[64 + tid] + rpart[128 + tid] + rpart[192 + tid];
      rrs[tid] = __builtin_amdgcn_rcpf(rt);
    }
    __syncthreads();

    // ---- um = (W*rr)^2, mask pad, den accumulate, bf16 umT write ----
#pragma unroll
    for (int pt = 0; pt < 4; pt++) {
      f32x4 rrv = *(const f32x4*)(const void*)&rrs[pt * 16 + quad * 4];
      float um[4];
#pragma unroll
      for (int r = 0; r < 4; r++) {
        float u = W[pt][r] * rrv[r];
        float m = u * u;
        um[r] = (pt * 16 + quad * 4 + r < np) ? m : 0.0f;
        den += um[r];
      }
      unsigned long long w64 = (unsigned long long)pkbf(um[0], um[1]) |
                               ((unsigned long long)pkbf(um[2], um[3]) << 32);
      *(unsigned long long*)(void*)&umT[(16 * w + col) * LDP + pt * 16 + quad * 4] = w64;
    }
    // no barrier: each wave reads back only the umT rows it wrote (lgkm order)

    // ---- GEMM2: D2[jt=w][dt] += um^T @ X ----
#pragma unroll
    for (int pb = 0; pb < 2; pb++) {
      bf16x8 au = *(const bf16x8*)(const void*)&umT[(16 * w + col) * LDP + pb * 32 + quad * 8];
#pragma unroll
      for (int dt = 0; dt < 4; dt++) {
        bf16x8 bx = *(const bf16x8*)(const void*)&XTb[(dt * 16 + col) * LDP + pb * 32 + quad * 8];
        D2[dt] = __builtin_amdgcn_mfma_f32_16x16x32_bf16(au, bx, D2[dt], 0, 0, 0);
      }
    }
  }

  // ---- epilogue: atomics into the single accumulator ----
  den += __shfl_xor(den, 16, 64);
  den += __shfl_xor(den, 32, 64);
  if (quad == 0) atomicAdd(&acc[CL * DM + 16 * w + col], den);
#pragma unroll
  for (int dt = 0; dt < 4; dt++)
#pragma unroll
    for (int r = 0; r < 4; r++)
      atomicAdd(&acc[(size_t)(16 * w + quad * 4 + r) * DM + dt * 16 + col], D2[dt][r]);
}

// 1-block finalize: C_new = num/den, zero acc for next pass, Frobenius diff vs
// C_old, freeze-on-convergence (out = C_old), last-iteration fallback (out = C_new).
__global__ __launch_bounds__(256)
void fcm_finalize(float* __restrict__ acc, float* __restrict__ Cnew,
                  const float* __restrict__ Cold, float* __restrict__ out,
                  int* __restrict__ done, int compute_diff, int last) {
  if (compute_diff && *done) return;
  __shared__ float sden[64];
  __shared__ float sdf[4];
  __shared__ float sdiff;
  int tid = threadIdx.x;
  if (tid < 64) { sden[tid] = acc[CL * DM + tid]; acc[CL * DM + tid] = 0.0f; }
  __syncthreads();
  float dsum = 0.0f;
#pragma unroll
  for (int q = 0; q < 16; q++) {
    int idx = q * 256 + tid;
    float c = acc[idx] / sden[idx >> 6];
    acc[idx] = 0.0f;
    Cnew[idx] = c;
    if (compute_diff) { float df = c - Cold[idx]; dsum = fmaf(df, df, dsum); }
  }
  if (!compute_diff) return;
  dsum = wave_sum(dsum);
  if ((tid & 63) == 0) sdf[tid >> 6] = dsum;
  __syncthreads();
  if (tid == 0) sdiff = (sdf[0] + sdf[1]) + (sdf[2] + sdf[3]);
  __syncthreads();
  if (sdiff < 1e-16f) {            // diff < 1e-8  <=>  diff^2 < 1e-16
#pragma unroll
    for (int q = 0; q < 16; q++) out[q * 256 + tid] = Cold[q * 256 + tid];
    if (tid == 0) *done = 1;
  } else if (last) {
#pragma unroll
    for (int q = 0; q < 16; q++) out[q * 256 + tid] = Cnew[q * 256 + tid];
  }
}

extern "C" void kernel_launch(void* const* d_in, const int* in_sizes, int n_in,
                              void* d_out, int out_size, void* d_ws, size_t ws_size,
                              hipStream_t stream) {
  const float* data = (const float*)d_in[0];
  const float* u0   = (const float*)d_in[1];
  float* out = (float*)d_out;
  int N = in_sizes[0] / DM;            // 300000
  int ntiles = (N + 63) / 64;          // 4688

  float* ws = (float*)d_ws;
  size_t Noff = ((size_t)N + 15) & ~(size_t)15;
  float* x2 = ws;                                      // N fp32
  unsigned short* xbf = (unsigned short*)(ws + Noff);  // N*64 bf16
  float* C0 = ws + Noff + (size_t)N * 32;
  float* C1 = C0 + CL * DM;
  float* acc = C1 + CL * DM;                           // 4160
  int* done = (int*)(acc + CL * DM + CL);

  hipLaunchKernelGGL(fcm_prep, dim3((N * 16 + 255) / 256), dim3(256), 0, stream,
                     data, x2, xbf, acc, done, N);
  hipLaunchKernelGGL((fcm_pass<true>), dim3(NB), dim3(256), 0, stream,
                     xbf, x2, u0, acc, done, N, ntiles);
  hipLaunchKernelGGL(fcm_finalize, dim3(1), dim3(256), 0, stream,
                     acc, C0, C1, out, done, 0, 0);

  float* bufs[2] = {C0, C1};
  for (int k = 0; k < MAX_ITER; k++) {
    float* Cc = bufs[k & 1];
    float* Cn = bufs[(k + 1) & 1];
    hipLaunchKernelGGL((fcm_pass<false>), dim3(NB), dim3(256), 0, stream,
                       xbf, x2, Cc, acc, done, N, ntiles);
    hipLaunchKernelGGL(fcm_finalize, dim3(1), dim3(256), 0, stream,
                       acc, Cn, Cc, out, done, 1, (k == MAX_ITER - 1) ? 1 : 0);
  }
}

// Round 7
// 430.294 us; speedup vs baseline: 3.7996x; 3.7996x over previous
//
#include <hip/hip_runtime.h>

// Fuzzy c-means on MI355X. N=300000, D=64, c=64, m=2 (p=2), 25 updates + init.
// R6 postmortem: atomic epilogue = 2.1M same-line device atomics/pass -> 4x
// regression. R7: revert to per-block partials + reduce (R5 structure, 427us),
// keep coalesced prep + conflict-free transpose, and restructure the pass:
// GEMM1 in POINT-major wave layout (wave = 16 points x 64 clusters, cf[4][2]
// B-frags in regs) -> cluster rowsum is in-wave DPP (no rpart/rrs LDS, saves
// 2 barriers/tile); umT via LDS (1 barrier); GEMM2 cluster-major as before.
// 3 barriers/tile (was 4). NB 512->768 (3 blocks/CU resident).

#define DM 64
#define CL 64
#define PARTIAL_STRIDE 4160      // 64*64 num + 64 den
#define MAX_ITER 25
#define MAX_BLOCKS 768
#define LDP 72                   // padded row (bf16): 144B, 16B-aligned rows

typedef __attribute__((ext_vector_type(8))) short bf16x8;   // MFMA A/B frag
typedef __attribute__((ext_vector_type(4))) float f32x4;    // MFMA C/D frag

__device__ __forceinline__ unsigned f2bf1(float f) {        // fp32 -> bf16 (RNE)
  unsigned u = __builtin_bit_cast(unsigned, f);
  return (u + 0x7FFFu + ((u >> 16) & 1u)) >> 16;
}
__device__ __forceinline__ unsigned pkbf(float a, float b) {
  return f2bf1(a) | (f2bf1(b) << 16);
}

// 64-lane sum, result uniform. Pure VALU (DPP) + readlane.
__device__ __forceinline__ float wave_sum(float v) {
#define DPPADD(ctrl, rmask)                                                  \
  v += __builtin_bit_cast(float, __builtin_amdgcn_update_dpp(                \
           0, __builtin_bit_cast(int, v), ctrl, rmask, 0xf, false));
  DPPADD(0x111, 0xf)   // row_shr:1
  DPPADD(0x112, 0xf)   // row_shr:2
  DPPADD(0x114, 0xf)   // row_shr:4
  DPPADD(0x118, 0xf)   // row_shr:8
  DPPADD(0x142, 0xa)   // row_bcast:15
  DPPADD(0x143, 0xc)   // row_bcast:31
#undef DPPADD
  return __builtin_bit_cast(
      float, __builtin_amdgcn_readlane(__builtin_bit_cast(int, v), 63));
}

// all-lanes sum within each 16-lane group (DPP butterfly), result in all 16.
__device__ __forceinline__ float group16_sum(float v) {
#define DPPADD(ctrl)                                                         \
  v += __builtin_bit_cast(float, __builtin_amdgcn_update_dpp(                \
           0, __builtin_bit_cast(int, v), ctrl, 0xf, 0xf, false));
  DPPADD(0xB1)    // quad_perm [1,0,3,2]
  DPPADD(0x4E)    // quad_perm [2,3,0,1]
  DPPADD(0x141)   // row_half_mirror
  DPPADD(0x140)   // row_mirror
#undef DPPADD
  return v;
}

// Coalesced prep: 16 lanes per row; float4 read, DPP x2, packed bf16 store.
__global__ void fcm_prep(const float* __restrict__ data, float* __restrict__ x2,
                         unsigned short* __restrict__ xbf, float* __restrict__ diffac,
                         int* __restrict__ done, int* __restrict__ ticket, int N) {
  int g = blockIdx.x * blockDim.x + threadIdx.x;
  if (g == 0) { *diffac = 0.0f; *done = 0; *ticket = 0; }
  int row = g >> 4;
  int c = g & 15;
  if (row < N) {
    float4 v = *(const float4*)(data + (size_t)row * DM + c * 4);
    float s = fmaf(v.x, v.x, fmaf(v.y, v.y, fmaf(v.z, v.z, v.w * v.w)));
    s = group16_sum(s);
    if (c == 0) x2[row] = s;
    uint2 pk = {pkbf(v.x, v.y), pkbf(v.z, v.w)};
    *(uint2*)(void*)(xbf + (size_t)row * DM + c * 4) = pk;
  }
}

// Fused pass. GEMM1 point-major (wave = 16 points, all 64 clusters in cf regs),
// in-wave rowsum; umT through LDS; GEMM2 cluster-major (wave = 16 clusters).
template <bool INIT>
__global__ __launch_bounds__(256, 3)
void fcm_pass(const unsigned short* __restrict__ xbf, const float* __restrict__ x2,
              const float* __restrict__ CU,   // INIT: u0[N][64]; else C[64][64]
              float* __restrict__ partial, const int* __restrict__ done,
              int N, int ntiles) {
  if (!INIT && *done) return;
  __shared__ __align__(16) unsigned short Xb[64 * LDP];   // X[p][d] bf16
  __shared__ __align__(16) unsigned short XTb[64 * LDP];  // X^T[d][p] bf16
  __shared__ __align__(16) unsigned short umT[64 * LDP];  // um^T[j][p] bf16
  __shared__ __align__(16) float rpart[4 * 64];           // per-wave den partials
  __shared__ __align__(16) float x2s[64];

  const int tid  = threadIdx.x;
  const int w    = __builtin_amdgcn_readfirstlane(tid >> 6);
  const int col  = tid & 15;
  const int quad = (tid >> 4) & 3;

  // ---- B-frags + c2 for ALL 64 clusters: cf[g] covers clusters g*16+col ----
  bf16x8 cf[4][2];
  float c2v[4];
  if (!INIT) {
#pragma unroll
    for (int g = 0; g < 4; g++) {
      const float* crow = CU + (size_t)(g * 16 + col) * DM;
      float4 ca = *(const float4*)(crow + quad * 8);
      float4 cb = *(const float4*)(crow + quad * 8 + 4);
      float4 cc = *(const float4*)(crow + 32 + quad * 8);
      float4 cd = *(const float4*)(crow + 32 + quad * 8 + 4);
      float cp = ca.x*ca.x + ca.y*ca.y + ca.z*ca.z + ca.w*ca.w
               + cb.x*cb.x + cb.y*cb.y + cb.z*cb.z + cb.w*cb.w
               + cc.x*cc.x + cc.y*cc.y + cc.z*cc.z + cc.w*cc.w
               + cd.x*cd.x + cd.y*cd.y + cd.z*cd.z + cd.w*cd.w;
      cp += __shfl_xor(cp, 16, 64);
      cp += __shfl_xor(cp, 32, 64);
      c2v[g] = cp;
      union { bf16x8 v; unsigned u[4]; } P0, P1;
      P0.u[0] = pkbf(ca.x, ca.y); P0.u[1] = pkbf(ca.z, ca.w);
      P0.u[2] = pkbf(cb.x, cb.y); P0.u[3] = pkbf(cb.z, cb.w);
      P1.u[0] = pkbf(cc.x, cc.y); P1.u[1] = pkbf(cc.z, cc.w);
      P1.u[2] = pkbf(cd.x, cd.y); P1.u[3] = pkbf(cd.z, cd.w);
      cf[g][0] = P0.v; cf[g][1] = P1.v;
    }
  }

  f32x4 D2[4];            // GEMM2 acc: clusters 16w.. x dims dt*16..
#pragma unroll
  for (int dt = 0; dt < 4; dt++) D2[dt] = f32x4{0.f, 0.f, 0.f, 0.f};
  float denacc[4] = {0.f, 0.f, 0.f, 0.f};   // den partial, cluster g*16+col

  for (int t = blockIdx.x; t < ntiles; t += gridDim.x) {
    const int base = t * 64;
    const int np = min(64, N - base);
    __syncthreads();   // (A) prev GEMM2 reads of XTb/umT done before overwrite

    // ---- Xb rows: b128 global -> b128 LDS (conflict-free) ----
    for (int i = tid; i < 512; i += 256) {
      int p = i >> 3;
      int d8 = (i & 7) * 8;
      bf16x8 v = bf16x8{0, 0, 0, 0, 0, 0, 0, 0};
      if (p < np) v = *(const bf16x8*)(xbf + (size_t)(base + p) * DM + d8);
      *(bf16x8*)(void*)&Xb[p * LDP + d8] = v;
    }
    // ---- XTb: in-register 2x2 bf16 transpose; p lane-fast b32 stores (2-way) ----
#pragma unroll
    for (int it = 0; it < 4; it++) {
      int idx = it * 256 + tid;
      int d = (idx >> 5) * 2;
      int p = (idx & 31) * 2;
      unsigned w0 = 0, w1 = 0;
      if (p < np)     w0 = *(const unsigned*)(xbf + (size_t)(base + p) * DM + d);
      if (p + 1 < np) w1 = *(const unsigned*)(xbf + (size_t)(base + p + 1) * DM + d);
      unsigned t0 = (w0 & 0xFFFFu) | (w1 << 16);
      unsigned t1 = (w0 >> 16) | (w1 & 0xFFFF0000u);
      *(unsigned*)(void*)&XTb[d * LDP + p] = t0;
      *(unsigned*)(void*)&XTb[(d + 1) * LDP + p] = t1;
    }
    if (tid < 64) x2s[tid] = (base + tid < N) ? x2[base + tid] : 0.0f;
    __syncthreads();   // (B) staging visible

    // ---- GEMM1 point-major: W[g][r] = weight(point 16w+quad*4+r, cluster g*16+col)
    float W[4][4];
    if (INIT) {
#pragma unroll
      for (int g = 0; g < 4; g++)
#pragma unroll
        for (int r = 0; r < 4; r++) {
          int pl = 16 * w + quad * 4 + r;
          W[g][r] = (pl < np)
              ? CU[(size_t)(base + pl) * CL + g * 16 + col] : 0.0f;
        }
    } else {
      bf16x8 a0 = *(const bf16x8*)(const void*)&Xb[(16 * w + col) * LDP + quad * 8];
      bf16x8 a1 = *(const bf16x8*)(const void*)&Xb[(16 * w + col) * LDP + 32 + quad * 8];
      f32x4 x2v = *(const f32x4*)(const void*)&x2s[16 * w + quad * 4];
#pragma unroll
      for (int g = 0; g < 4; g++) {
        f32x4 s = f32x4{0.f, 0.f, 0.f, 0.f};
        s = __builtin_amdgcn_mfma_f32_16x16x32_bf16(a0, cf[g][0], s, 0, 0, 0);
        s = __builtin_amdgcn_mfma_f32_16x16x32_bf16(a1, cf[g][1], s, 0, 0, 0);
#pragma unroll
        for (int r = 0; r < 4; r++) {
          float dist = fmaxf(fmaf(-2.0f, s[r], x2v[r] + c2v[g]), 0.0f);
          W[g][r] = __builtin_amdgcn_rcpf(dist);   // d^(-p/2), p=2
        }
      }
    }

    // ---- rowsum over all 64 clusters: in-wave (4 groups + 16-lane DPP) ----
    float rr[4];
#pragma unroll
    for (int r = 0; r < 4; r++) {
      float s = (W[0][r] + W[1][r]) + (W[2][r] + W[3][r]);
      rr[r] = __builtin_amdgcn_rcpf(group16_sum(s));
    }

    // ---- um = (W*rr)^2, mask pad, den partials, umT b64 writes (own slab) ----
#pragma unroll
    for (int g = 0; g < 4; g++) {
      float um[4];
#pragma unroll
      for (int r = 0; r < 4; r++) {
        float u = W[g][r] * rr[r];
        float m = u * u;
        um[r] = (16 * w + quad * 4 + r < np) ? m : 0.0f;
      }
      denacc[g] += ((um[0] + um[1]) + (um[2] + um[3]));
      unsigned long long w64 = (unsigned long long)pkbf(um[0], um[1]) |
                               ((unsigned long long)pkbf(um[2], um[3]) << 32);
      *(unsigned long long*)(void*)&umT[(g * 16 + col) * LDP + 16 * w + quad * 4] = w64;
    }
    __syncthreads();   // (C) umT fully written

    // ---- GEMM2 cluster-major: D2[dt] += um^T[16w..] @ X ----
#pragma unroll
    for (int pb = 0; pb < 2; pb++) {
      bf16x8 au = *(const bf16x8*)(const void*)&umT[(16 * w + col) * LDP + pb * 32 + quad * 8];
#pragma unroll
      for (int dt = 0; dt < 4; dt++) {
        bf16x8 bx = *(const bf16x8*)(const void*)&XTb[(dt * 16 + col) * LDP + pb * 32 + quad * 8];
        D2[dt] = __builtin_amdgcn_mfma_f32_16x16x32_bf16(au, bx, D2[dt], 0, 0, 0);
      }
    }
  }

  // ---- epilogue: fold den quads once, cross-wave via rpart, store partial ----
#pragma unroll
  for (int g = 0; g < 4; g++) {
    float dv = denacc[g];
    dv += __shfl_xor(dv, 16, 64);
    dv += __shfl_xor(dv, 32, 64);
    if (quad == 0) rpart[w * 64 + g * 16 + col] = dv;
  }
  __syncthreads();
  float* pb = partial + (size_t)blockIdx.x * PARTIAL_STRIDE;
  if (tid < 64)
    pb[CL * DM + tid] = (rpart[tid] + rpart[64 + tid]) + (rpart[128 + tid] + rpart[192 + tid]);
#pragma unroll
  for (int dt = 0; dt < 4; dt++)
#pragma unroll
    for (int r = 0; r < 4; r++)
      pb[(size_t)(16 * w + quad * 4 + r) * DM + dt * 16 + col] = D2[dt][r];
}

// Sum partials -> C_new; Frobenius diff; last block (ticket) does convergence check.
__global__ __launch_bounds__(1024, 1)
void fcm_reduce(const float* __restrict__ partial, float* __restrict__ Cnew,
                const float* __restrict__ Cold, float* __restrict__ out,
                float* __restrict__ diffac, int* __restrict__ done,
                int* __restrict__ ticket, int compute_diff, int nb) {
  if (compute_diff && *done) return;
  __shared__ float sm[16 * 64];
  __shared__ float sden[1024];
  __shared__ int lastflag;
  __shared__ float sdiff;
  int j = blockIdx.x;
  int tid = threadIdx.x;
  int d = tid & 63;
  int slice = tid >> 6;
  float s = 0.0f;
  for (int b = slice; b < nb; b += 16)
    s += partial[(size_t)b * PARTIAL_STRIDE + j * DM + d];
  sm[slice * 64 + d] = s;
  float dv = 0.0f;
  for (int b = tid; b < nb; b += 1024)
    dv += partial[(size_t)b * PARTIAL_STRIDE + CL * DM + j];
  sden[tid] = dv;
  __syncthreads();
#pragma unroll
  for (int st = 8; st; st >>= 1) {
    if (slice < st) sm[slice * 64 + d] += sm[(slice + st) * 64 + d];
    __syncthreads();
  }
#pragma unroll
  for (int st = 512; st >= 64; st >>= 1) {
    if (tid < st) sden[tid] += sden[tid + st];
    __syncthreads();
  }
  if (tid < 64) {
    float denj = wave_sum(sden[tid]);
    float c = sm[tid] / denj;
    Cnew[j * DM + tid] = c;
    if (compute_diff) {
      float df = c - Cold[j * DM + tid];
      float tot = wave_sum(df * df);
      if (tid == 0) atomicAdd(diffac, tot);
    }
  }
  if (!compute_diff) return;
  __syncthreads();
  if (tid == 0) {
    __threadfence();
    int t = atomicAdd(ticket, 1);
    lastflag = (t == (int)gridDim.x - 1);
  }
  __syncthreads();
  if (!lastflag) return;
  if (tid == 0) sdiff = atomicAdd(diffac, 0.0f);
  __syncthreads();
  if (sdiff < 1e-16f) {                 // diff < 1e-8  <=>  diff^2 < 1e-16
    for (int i = tid; i < CL * DM; i += 1024) out[i] = Cold[i];
    if (tid == 0) *done = 1;
  }
  if (tid == 0) { *diffac = 0.0f; *ticket = 0; }
}

// If never converged, V = C_25.
__global__ void fcm_final(const float* __restrict__ Clast, float* __restrict__ out,
                          const int* __restrict__ done) {
  if (*done) return;
  int i = blockIdx.x * blockDim.x + threadIdx.x;
  if (i < CL * DM) out[i] = Clast[i];
}

extern "C" void kernel_launch(void* const* d_in, const int* in_sizes, int n_in,
                              void* d_out, int out_size, void* d_ws, size_t ws_size,
                              hipStream_t stream) {
  const float* data = (const float*)d_in[0];
  const float* u0   = (const float*)d_in[1];
  float* out = (float*)d_out;
  int N = in_sizes[0] / DM;            // 300000
  int ntiles = (N + 63) / 64;          // 4688

  float* ws = (float*)d_ws;
  size_t Noff = ((size_t)N + 15) & ~(size_t)15;
  float* x2 = ws;                                      // N fp32
  unsigned short* xbf = (unsigned short*)(ws + Noff);  // N*64 bf16
  float* C0 = ws + Noff + (size_t)N * 32;
  float* C1 = C0 + CL * DM;
  float* diffac = C1 + CL * DM;
  int* done = (int*)(diffac + 1);
  int* ticket = (int*)(diffac + 2);
  float* partial = diffac + 16;

  size_t used = Noff + (size_t)N * 32 + 2 * CL * DM + 16;
  size_t avail = (ws_size / 4 > used) ? (ws_size / 4 - used) / PARTIAL_STRIDE : 0;
  int nb = (int)(avail < MAX_BLOCKS ? avail : MAX_BLOCKS);
  if (nb < 1) nb = 1;

  hipLaunchKernelGGL(fcm_prep, dim3((N * 16 + 255) / 256), dim3(256), 0, stream,
                     data, x2, xbf, diffac, done, ticket, N);
  hipLaunchKernelGGL((fcm_pass<true>), dim3(nb), dim3(256), 0, stream,
                     xbf, x2, u0, partial, done, N, ntiles);
  hipLaunchKernelGGL(fcm_reduce, dim3(64), dim3(1024), 0, stream,
                     partial, C0, C1, out, diffac, done, ticket, 0, nb);

  float* bufs[2] = {C0, C1};
  for (int k = 0; k < MAX_ITER; k++) {
    float* Cc = bufs[k & 1];
    float* Cn = bufs[(k + 1) & 1];
    hipLaunchKernelGGL((fcm_pass<false>), dim3(nb), dim3(256), 0, stream,
                       xbf, x2, Cc, partial, done, N, ntiles);
    hipLaunchKernelGGL(fcm_reduce, dim3(64), dim3(1024), 0, stream,
                       partial, Cn, Cc, out, diffac, done, ticket, 1, nb);
  }
  hipLaunchKernelGGL(fcm_final, dim3(16), dim3(256), 0, stream,
                     bufs[1], out, done);
}